// Round 23
// baseline (140.373 us; speedup 1.0000x reference)
//
#include <hip/hip_runtime.h>
#include <hip/hip_bf16.h>

// B=2, S=2048, D=1024, H=16, hd=64.
// prep (weights cast + mask bitpack) -> fused QKV GEMM (fp32 A reg-staged,
// R23: 64x128 tiles, grid 1536 = 6 blocks/CU for latency hiding; A-prefetch
// after barrier per R20) -> flash attention (R15/R20 structure) -> out GEMM.

typedef float f32x4 __attribute__((ext_vector_type(4)));
typedef float f32x16 __attribute__((ext_vector_type(16)));
typedef short s16x8 __attribute__((ext_vector_type(8)));
typedef unsigned u32x4 __attribute__((ext_vector_type(4)));

#if __has_builtin(__builtin_amdgcn_exp2f)
#define EXP2F __builtin_amdgcn_exp2f
#else
#define EXP2F exp2f
#endif

#if __has_builtin(__builtin_amdgcn_rcpf)
#define RCPF __builtin_amdgcn_rcpf
#else
#define RCPF(x) (1.0f / (x))
#endif

// XOR swizzle for [64][64] bf16 LDS tiles: e = element col offset (mult of 8)
#define KSWZ(row, e) ((row) * 64 + ((e) ^ (((row) & 7) << 3)))

__device__ __forceinline__ void gload16(const void* g, void* l) {
  __builtin_amdgcn_global_load_lds(
      (const __attribute__((address_space(1))) unsigned int*)g,
      (__attribute__((address_space(3))) unsigned int*)l, 16, 0, 0);
}

__device__ __forceinline__ f32x4 mfma16x16x32(s16x8 a, s16x8 b, f32x4 c) {
  return __builtin_amdgcn_mfma_f32_16x16x32_bf16(a, b, c, 0, 0, 0);
}

__device__ __forceinline__ f32x16 mfma32x32x16(s16x8 a, s16x8 b, f32x16 c) {
  return __builtin_amdgcn_mfma_f32_32x32x16_bf16(a, b, c, 0, 0, 0);
}

__device__ __forceinline__ unsigned short bf16bits(float x) {
  __hip_bfloat16 h = __float2bfloat16(x);
  return *reinterpret_cast<unsigned short*>(&h);
}

// pack 2 f32 -> 2 bf16 (RNE), single instruction
__device__ __forceinline__ unsigned cvt_pk_bf16(float lo, float hi) {
  unsigned r;
  asm("v_cvt_pk_bf16_f32 %0, %1, %2" : "=v"(r) : "v"(lo), "v"(hi));
  return r;
}

// --- prep: weights cast + mask bitpack -----------------------------------
__global__ __launch_bounds__(256) void prep_kernel(
    const float* __restrict__ Wq, const float* __restrict__ Wk,
    const float* __restrict__ Wv, const float* __restrict__ Wo,
    const int* __restrict__ mask, __hip_bfloat16* wqb, __hip_bfloat16* wkb,
    __hip_bfloat16* wvb, __hip_bfloat16* wob, unsigned long long* bits) {
  const int bid = blockIdx.x;
  if (bid < 4096) {
    int j = bid * 256 + threadIdx.x;
    int seg = j >> 18;
    int off = j & 262143;
    const float* src = seg == 0 ? Wq : seg == 1 ? Wk : seg == 2 ? Wv : Wo;
    __hip_bfloat16* dst = seg == 0 ? wqb : seg == 1 ? wkb : seg == 2 ? wvb : wob;
    float4 x = ((const float4*)src)[off];
    ushort4 o;
    o.x = bf16bits(x.x);
    o.y = bf16bits(x.y);
    o.z = bf16bits(x.z);
    o.w = bf16bits(x.w);
    ((ushort4*)dst)[off] = o;
  } else {
    const int base = (bid - 4096) * 16;
    const int wv_ = threadIdx.x >> 6;
    const int lane = threadIdx.x & 63;
#pragma unroll
    for (int it = 0; it < 4; ++it) {
      int gw = base + it * 4 + wv_;
      int mv = mask[(size_t)gw * 64 + lane];
      unsigned long long bm = __ballot(mv != 0);
      if (lane == 0) bits[gw] = bm;
    }
  }
}

// --- fused QKV GEMM: fp32 A, 64x128 tiles, 1536 blocks -------------------
// z=0: Qp = (q@Wq^T+bq)*0.125*log2e ; z=1: Kp ; z=2: Vt[b,h,d,s].
__global__ __launch_bounds__(256) void gemm_qkv(
    const float* __restrict__ qf, const float* __restrict__ kf,
    const float* __restrict__ vf, const __hip_bfloat16* __restrict__ wq,
    const __hip_bfloat16* __restrict__ wk,
    const __hip_bfloat16* __restrict__ wv, const float* __restrict__ bq,
    const float* __restrict__ bk_, const float* __restrict__ bv_,
    __hip_bfloat16* __restrict__ Qp, __hip_bfloat16* __restrict__ Kp,
    __hip_bfloat16* __restrict__ Vtp) {
  constexpr int N = 1024, K = 1024;
  // grid (8, 64, 3) = 1536; XCD-chunked swizzle, 192 per XCD
  const int fid = blockIdx.x + 8 * (blockIdx.y + 64 * blockIdx.z);
  const int nid = (fid & 7) * 192 + (fid >> 3);
  const int bx = nid & 7;
  const int by = (nid >> 3) & 63;
  const int z = nid >> 9;

  const float* Af = z == 0 ? qf : z == 1 ? kf : vf;
  const __hip_bfloat16* Bw = z == 0 ? wq : z == 1 ? wk : wv;
  const float* bias = z == 0 ? bq : z == 1 ? bk_ : bv_;

  __shared__ __hip_bfloat16 sA[64 * 32];
  __shared__ __hip_bfloat16 sB[128 * 32];
  const int tid = threadIdx.x;
  const int lane = tid & 63;
  const int wid = tid >> 6;
  const int wr = wid >> 1;  // 0..1 : 32-row group
  const int wc = wid & 1;   // 0..1 : 64-col group
  const int m0 = by * 64;
  const int n0 = bx * 128;
  const int srow = tid >> 2;       // 0..63
  const int scol = (tid & 3) * 8;  // 0..24

  f32x4 acc[2][4] = {};
  const int fr = lane & 15;
  const int fk = (lane >> 4) * 8;

  const float* a0base = Af + (size_t)(m0 + srow) * K + scol;

  // prologue: A(0) into regs
  float4 x0 = *(const float4*)(a0base);
  float4 x1 = *(const float4*)(a0base + 4);

  for (int k0 = 0; k0 < K; k0 += 32) {
    // write A(k0) from regs (cvt_pk) into LDS; B via async gload
    u32x4 pa = {cvt_pk_bf16(x0.x, x0.y), cvt_pk_bf16(x0.z, x0.w),
                cvt_pk_bf16(x1.x, x1.y), cvt_pk_bf16(x1.z, x1.w)};
    *(u32x4*)(sA + tid * 8) = pa;
    gload16(Bw + (size_t)(n0 + srow) * K + k0 + scol, sB + tid * 8);
    gload16(Bw + (size_t)(n0 + 64 + srow) * K + k0 + scol, sB + 2048 + tid * 8);
    __syncthreads();

    // issue A(k0+32) loads AFTER the barrier -> hidden under compute
    if (k0 + 32 < K) {
      x0 = *(const float4*)(a0base + k0 + 32);
      x1 = *(const float4*)(a0base + k0 + 36);
    }

    s16x8 af[2], bfr[4];
#pragma unroll
    for (int mi = 0; mi < 2; ++mi)
      af[mi] = *(const s16x8*)(sA + (wr * 32 + mi * 16 + fr) * 32 + fk);
#pragma unroll
    for (int ni = 0; ni < 4; ++ni)
      bfr[ni] = *(const s16x8*)(sB + (wc * 64 + ni * 16 + fr) * 32 + fk);
#pragma unroll
    for (int mi = 0; mi < 2; ++mi)
#pragma unroll
      for (int ni = 0; ni < 4; ++ni)
        acc[mi][ni] = mfma16x16x32(af[mi], bfr[ni], acc[mi][ni]);
    __syncthreads();
  }

  const int fq = (lane >> 4) * 4;
#pragma unroll
  for (int mi = 0; mi < 2; ++mi) {
#pragma unroll
    for (int ni = 0; ni < 4; ++ni) {
      const int row = m0 + wr * 32 + mi * 16 + fq;
      const int col = n0 + wc * 64 + ni * 16 + fr;
      const float bv = bias[col];
      f32x4 v = acc[mi][ni];
      if (z == 2) {
        ushort4 pk;
        pk.x = bf16bits(v[0] + bv);
        pk.y = bf16bits(v[1] + bv);
        pk.z = bf16bits(v[2] + bv);
        pk.w = bf16bits(v[3] + bv);
        const int bb = row >> 11;
        const int s = row & 2047;
        size_t vtrow = ((size_t)(bb * 16) + (col >> 6)) * 64 + (col & 63);
        *(ushort4*)(Vtp + vtrow * 2048 + s) = pk;
      } else if (z == 1) {
#pragma unroll
        for (int r = 0; r < 4; ++r)
          Kp[(size_t)(row + r) * N + col] = __float2bfloat16(v[r] + bv);
      } else {
#pragma unroll
        for (int r = 0; r < 4; ++r)
          Qp[(size_t)(row + r) * N + col] =
              __float2bfloat16((v[r] + bv) * 0.18033688f);  // 0.125*log2(e)
      }
    }
  }
}

// --- out GEMM: C = A @ Bw^T + bias (f32 out), 64x128 tile, 512 blocks ----
__global__ __launch_bounds__(256) void gemm_out(
    const __hip_bfloat16* __restrict__ A, const __hip_bfloat16* __restrict__ Bw,
    const float* __restrict__ bias, float* __restrict__ Cout) {
  constexpr int N = 1024, K = 1024;
  const int fid = blockIdx.x + 8 * blockIdx.y;
  const int nid = (fid & 7) * 64 + (fid >> 3);
  const int bx = nid & 7;
  const int by = nid >> 3;  // 0..63

  __shared__ __hip_bfloat16 sA[64 * 32];
  __shared__ __hip_bfloat16 sB[128 * 32];
  const int tid = threadIdx.x;
  const int lane = tid & 63;
  const int wid = tid >> 6;
  const int wr = wid >> 1;
  const int wc = wid & 1;
  const int m0 = by * 64;
  const int n0 = bx * 128;
  const int srow = tid >> 2;
  const int scol = (tid & 3) * 8;

  f32x4 acc[2][4] = {};
  const int fr = lane & 15;
  const int fk = (lane >> 4) * 8;

  for (int k0 = 0; k0 < K; k0 += 32) {
    gload16(A + (size_t)(m0 + srow) * K + k0 + scol, sA + tid * 8);
    gload16(Bw + (size_t)(n0 + srow) * K + k0 + scol, sB + tid * 8);
    gload16(Bw + (size_t)(n0 + 64 + srow) * K + k0 + scol, sB + 2048 + tid * 8);
    __syncthreads();
    s16x8 af[2], bfr[4];
#pragma unroll
    for (int mi = 0; mi < 2; ++mi)
      af[mi] = *(const s16x8*)(sA + (wr * 32 + mi * 16 + fr) * 32 + fk);
#pragma unroll
    for (int ni = 0; ni < 4; ++ni)
      bfr[ni] = *(const s16x8*)(sB + (wc * 64 + ni * 16 + fr) * 32 + fk);
#pragma unroll
    for (int mi = 0; mi < 2; ++mi)
#pragma unroll
      for (int ni = 0; ni < 4; ++ni)
        acc[mi][ni] = mfma16x16x32(af[mi], bfr[ni], acc[mi][ni]);
    __syncthreads();
  }

  const int fq = (lane >> 4) * 4;
#pragma unroll
  for (int mi = 0; mi < 2; ++mi) {
#pragma unroll
    for (int ni = 0; ni < 4; ++ni) {
      const int row = m0 + wr * 32 + mi * 16 + fq;
      const int col = n0 + wc * 64 + ni * 16 + fr;
      const float bv = bias[col];
      f32x4 v = acc[mi][ni];
#pragma unroll
      for (int r = 0; r < 4; ++r)
        Cout[(size_t)(row + r) * N + col] = v[r] + bv;
    }
  }
}

// --- flash attention: 32x32 MFMA, in-register P, KVBLK=128, ILP-paired ---
__global__ __launch_bounds__(256) void attn_kernel(
    const __hip_bfloat16* __restrict__ Q, const __hip_bfloat16* __restrict__ Kb,
    const __hip_bfloat16* __restrict__ Vt,
    const unsigned long long* __restrict__ gbits,
    __hip_bfloat16* __restrict__ O, int S) {
  __shared__ __hip_bfloat16 sK[2][2][64 * 64];   // [buf][kv-half][kv][d]
  __shared__ __hip_bfloat16 sVT[2][2][64 * 64];  // [buf][kv-half][d][kv]

  const int tid = threadIdx.x;
  const int lane = tid & 63;
  const int wid = tid >> 6;  // 0..3
  const int fid = blockIdx.x + 16 * blockIdx.y;
  const int nid = (fid & 7) * 64 + (fid >> 3);
  const int qblk = nid & 15;
  const int bh = nid >> 4;
  const int q0 = qblk * 128;
  const int b = bh >> 4;
  const size_t rowbase = (size_t)b * S * 1024 + (size_t)(bh & 15) * 64;
  const size_t vtbase = (size_t)bh * 64;

  const int l31 = lane & 31;
  const int h2 = lane >> 5;

  const int qw = q0 + wid * 32 + l31;
  s16x8 aq[4];
#pragma unroll
  for (int c2 = 0; c2 < 4; ++c2)
    aq[c2] =
        *(const s16x8*)(Q + rowbase + (size_t)qw * 1024 + c2 * 16 + h2 * 8);

  f32x16 o0 = {}, o1 = {}, lacc = {};
  s16x8 ones;
#pragma unroll
  for (int j = 0; j < 8; ++j) ones[j] = (short)0x3F80;  // bf16 1.0

  const unsigned long long* bitrow = gbits + ((size_t)b * S + qw) * (S / 64);

  const int lrow = lane >> 3;
  const int lg = ((lane & 7) ^ lrow) * 8;
  auto STAGE = [&](const int buf, int kv0) __attribute__((always_inline)) {
#pragma unroll
    for (int h = 0; h < 2; ++h) {
#pragma unroll
      for (int i = 0; i < 2; ++i) {
        const int rr = wid * 2 + i;
        const int rowi = rr * 8 + lrow;
        gload16(Kb + rowbase + (size_t)(kv0 + h * 64 + rowi) * 1024 + lg,
                &sK[buf][h][rr * 512 + lane * 8]);
        gload16(Vt + (vtbase + rowi) * 2048 + kv0 + h * 64 + lg,
                &sVT[buf][h][rr * 512 + lane * 8]);
      }
    }
  };

  // softmax+pack one 32-kv subtile (p = bits(exp2(s)) & sext(maskbit))
  auto packP = [&](const f32x16& sc, unsigned mm, s16x8& A0,
                   s16x8& A1) __attribute__((always_inline)) {
    float p[16];
#pragma unroll
    for (int reg = 0; reg < 16; ++reg) {
      float e = EXP2F(sc[reg]);
      const int bit = (reg & 3) + 8 * (reg >> 2);
      int m = ((int)(mm << (31 - bit))) >> 31;
      unsigned pe = __builtin_bit_cast(unsigned, e) & (unsigned)m;
      p[reg] = __builtin_bit_cast(float, pe);
    }
    unsigned w0t0 = cvt_pk_bf16(p[0], p[1]), w0t1 = cvt_pk_bf16(p[2], p[3]);
    unsigned w1t0 = cvt_pk_bf16(p[4], p[5]), w1t1 = cvt_pk_bf16(p[6], p[7]);
    unsigned w2t0 = cvt_pk_bf16(p[8], p[9]), w2t1 = cvt_pk_bf16(p[10], p[11]);
    unsigned w3t0 = cvt_pk_bf16(p[12], p[13]), w3t1 = cvt_pk_bf16(p[14], p[15]);
    asm("v_permlane32_swap_b32 %0, %1" : "+v"(w0t0), "+v"(w1t0));
    asm("v_permlane32_swap_b32 %0, %1" : "+v"(w0t1), "+v"(w1t1));
    asm("v_permlane32_swap_b32 %0, %1" : "+v"(w2t0), "+v"(w3t0));
    asm("v_permlane32_swap_b32 %0, %1" : "+v"(w2t1), "+v"(w3t1));
    u32x4 qa0 = {w0t0, w0t1, w1t0, w1t1};
    u32x4 qa1 = {w2t0, w2t1, w3t0, w3t1};
    A0 = __builtin_bit_cast(s16x8, qa0);
    A1 = __builtin_bit_cast(s16x8, qa1);
  };

  STAGE(0, 0);
  unsigned long long wc0 = bitrow[0], wc1 = bitrow[1];
  unsigned long long wn0 = 0, wn1 = 0;

  const int ntiles = S / 128;  // 16

  auto tile_body = [&](const int buf, int t) __attribute__((always_inline)) {
    __syncthreads();

    if (t + 1 < ntiles) {
      STAGE(buf ^ 1, (t + 1) * 128);
      wn0 = bitrow[2 * t + 2];
      wn1 = bitrow[2 * t + 3];
    }

#pragma unroll
    for (int kh = 0; kh < 2; ++kh) {
      const __hip_bfloat16* sKc = &sK[buf][kh][0];
      const __hip_bfloat16* sVc = &sVT[buf][kh][0];
      const unsigned long long wcv = kh ? wc1 : wc0;

      f32x16 s0 = {}, s1 = {};
#pragma unroll
      for (int c2 = 0; c2 < 4; ++c2) {
        s16x8 ak0 = *(const s16x8*)(sKc + KSWZ(l31, c2 * 16 + h2 * 8));
        s16x8 ak1 = *(const s16x8*)(sKc + KSWZ(32 + l31, c2 * 16 + h2 * 8));
        s0 = mfma32x32x16(ak0, aq[c2], s0);
        s1 = mfma32x32x16(ak1, aq[c2], s1);
      }

      s16x8 v000 = *(const s16x8*)(sVc + KSWZ(l31, h2 * 8));
      s16x8 v001 = *(const s16x8*)(sVc + KSWZ(l31, 16 + h2 * 8));
      s16x8 v010 = *(const s16x8*)(sVc + KSWZ(32 + l31, h2 * 8));
      s16x8 v011 = *(const s16x8*)(sVc + KSWZ(32 + l31, 16 + h2 * 8));
      s16x8 v100 = *(const s16x8*)(sVc + KSWZ(l31, 32 + h2 * 8));
      s16x8 v101 = *(const s16x8*)(sVc + KSWZ(l31, 32 + 16 + h2 * 8));
      s16x8 v110 = *(const s16x8*)(sVc + KSWZ(32 + l31, 32 + h2 * 8));
      s16x8 v111 = *(const s16x8*)(sVc + KSWZ(32 + l31, 32 + 16 + h2 * 8));

      s16x8 A00, A01, A10, A11;
      packP(s0, (unsigned)(wcv >> (h2 * 4)), A00, A01);
      o0 = mfma32x32x16(A00, v000, o0);
      o1 = mfma32x32x16(A00, v010, o1);
      lacc = mfma32x32x16(A00, ones, lacc);
      packP(s1, (unsigned)(wcv >> (32 + h2 * 4)), A10, A11);
      o0 = mfma32x32x16(A01, v001, o0);
      o1 = mfma32x32x16(A01, v011, o1);
      lacc = mfma32x32x16(A01, ones, lacc);
      o0 = mfma32x32x16(A10, v100, o0);
      o1 = mfma32x32x16(A10, v110, o1);
      lacc = mfma32x32x16(A10, ones, lacc);
      o0 = mfma32x32x16(A11, v101, o0);
      o1 = mfma32x32x16(A11, v111, o1);
      lacc = mfma32x32x16(A11, ones, lacc);
    }
    wc0 = wn0;
    wc1 = wn1;
  };

  for (int tb = 0; tb < ntiles / 2; ++tb) {
    tile_body(0, 2 * tb);
    tile_body(1, 2 * tb + 1);
  }

#pragma unroll
  for (int reg = 0; reg < 16; ++reg) {
    const float inv = RCPF(lacc[reg]);
    const int qr = (reg & 3) + 8 * (reg >> 2) + 4 * h2;
    const size_t base = rowbase + (size_t)(q0 + wid * 32 + qr) * 1024;
    O[base + 0 * 32 + l31] = __float2bfloat16(o0[reg] * inv);
    O[base + 1 * 32 + l31] = __float2bfloat16(o1[reg] * inv);
  }
}

extern "C" void kernel_launch(void* const* d_in, const int* in_sizes, int n_in,
                              void* d_out, int out_size, void* d_ws,
                              size_t ws_size, hipStream_t stream) {
  const float* query = (const float*)d_in[0];
  const float* key = (const float*)d_in[1];
  const float* value = (const float*)d_in[2];
  const int* mask = (const int*)d_in[3];
  const float* Wq = (const float*)d_in[4];
  const float* bq = (const float*)d_in[5];
  const float* Wk = (const float*)d_in[6];
  const float* bk = (const float*)d_in[7];
  const float* Wv = (const float*)d_in[8];
  const float* bv = (const float*)d_in[9];
  const float* Wo = (const float*)d_in[10];
  const float* bo = (const float*)d_in[11];

  const int B = 2, S = 2048, D = 1024;
  const int M = B * S;
  const size_t MB = 1024u * 1024u;

  char* ws = (char*)d_ws;
  __hip_bfloat16* wqb = (__hip_bfloat16*)(ws + 24 * MB);
  __hip_bfloat16* wkb = (__hip_bfloat16*)(ws + 26 * MB);
  __hip_bfloat16* wvb = (__hip_bfloat16*)(ws + 28 * MB);
  __hip_bfloat16* wob = (__hip_bfloat16*)(ws + 30 * MB);
  __hip_bfloat16* Qp = (__hip_bfloat16*)(ws + 32 * MB);
  __hip_bfloat16* Kp = (__hip_bfloat16*)(ws + 40 * MB);
  __hip_bfloat16* Vtp = (__hip_bfloat16*)(ws + 48 * MB);
  __hip_bfloat16* Ob = (__hip_bfloat16*)(ws + 56 * MB);
  unsigned long long* bits = (unsigned long long*)(ws + 64 * MB);

  prep_kernel<<<dim3(12288), dim3(256), 0, stream>>>(
      Wq, Wk, Wv, Wo, mask, wqb, wkb, wvb, wob, bits);

  gemm_qkv<<<dim3(8, 64, 3), dim3(256), 0, stream>>>(
      query, key, value, wqb, wkb, wvb, bq, bk, bv, Qp, Kp, Vtp);

  attn_kernel<<<dim3(S / 128, B * 16), dim3(256), 0, stream>>>(Qp, Kp, Vtp,
                                                               bits, Ob, S);

  gemm_out<<<dim3(D / 128, M / 64), dim3(256), 0, stream>>>(Ob, wob, bo,
                                                            (float*)d_out);
}

// Round 24
// 123.925 us; speedup vs baseline: 1.1327x; 1.1327x over previous
//
#include <hip/hip_runtime.h>
#include <hip/hip_bf16.h>

// B=2, S=2048, D=1024, H=16, hd=64.  (R24 = R20 verbatim, best measured.)
// prep (weights cast + mask bitpack) -> fused QKV GEMM reading fp32 q/k/v
// directly (A(k+1) prefetched into regs AFTER the mid-barrier so HBM latency
// hides under compute(k); cvt+ds_write next iter) -> flash attention
// (32x32x16 MFMA, in-register P via cvt_pk+permlane32_swap, KVBLK=128 dbuf,
// ILP-paired QK^T, spaced PV) -> out GEMM (64x128 tiles).

typedef float f32x4 __attribute__((ext_vector_type(4)));
typedef float f32x16 __attribute__((ext_vector_type(16)));
typedef short s16x8 __attribute__((ext_vector_type(8)));
typedef unsigned u32x4 __attribute__((ext_vector_type(4)));

#if __has_builtin(__builtin_amdgcn_exp2f)
#define EXP2F __builtin_amdgcn_exp2f
#else
#define EXP2F exp2f
#endif

#if __has_builtin(__builtin_amdgcn_rcpf)
#define RCPF __builtin_amdgcn_rcpf
#else
#define RCPF(x) (1.0f / (x))
#endif

// XOR swizzle for [64][64] bf16 LDS tiles: e = element col offset (mult of 8)
#define KSWZ(row, e) ((row) * 64 + ((e) ^ (((row) & 7) << 3)))

__device__ __forceinline__ void gload16(const void* g, void* l) {
  __builtin_amdgcn_global_load_lds(
      (const __attribute__((address_space(1))) unsigned int*)g,
      (__attribute__((address_space(3))) unsigned int*)l, 16, 0, 0);
}

__device__ __forceinline__ f32x4 mfma16x16x32(s16x8 a, s16x8 b, f32x4 c) {
  return __builtin_amdgcn_mfma_f32_16x16x32_bf16(a, b, c, 0, 0, 0);
}

__device__ __forceinline__ f32x16 mfma32x32x16(s16x8 a, s16x8 b, f32x16 c) {
  return __builtin_amdgcn_mfma_f32_32x32x16_bf16(a, b, c, 0, 0, 0);
}

__device__ __forceinline__ unsigned short bf16bits(float x) {
  __hip_bfloat16 h = __float2bfloat16(x);
  return *reinterpret_cast<unsigned short*>(&h);
}

// pack 2 f32 -> 2 bf16 (RNE), single instruction
__device__ __forceinline__ unsigned cvt_pk_bf16(float lo, float hi) {
  unsigned r;
  asm("v_cvt_pk_bf16_f32 %0, %1, %2" : "=v"(r) : "v"(lo), "v"(hi));
  return r;
}

// --- prep: weights cast + mask bitpack -----------------------------------
__global__ __launch_bounds__(256) void prep_kernel(
    const float* __restrict__ Wq, const float* __restrict__ Wk,
    const float* __restrict__ Wv, const float* __restrict__ Wo,
    const int* __restrict__ mask, __hip_bfloat16* wqb, __hip_bfloat16* wkb,
    __hip_bfloat16* wvb, __hip_bfloat16* wob, unsigned long long* bits) {
  const int bid = blockIdx.x;
  if (bid < 4096) {
    int j = bid * 256 + threadIdx.x;
    int seg = j >> 18;
    int off = j & 262143;
    const float* src = seg == 0 ? Wq : seg == 1 ? Wk : seg == 2 ? Wv : Wo;
    __hip_bfloat16* dst = seg == 0 ? wqb : seg == 1 ? wkb : seg == 2 ? wvb : wob;
    float4 x = ((const float4*)src)[off];
    ushort4 o;
    o.x = bf16bits(x.x);
    o.y = bf16bits(x.y);
    o.z = bf16bits(x.z);
    o.w = bf16bits(x.w);
    ((ushort4*)dst)[off] = o;
  } else {
    const int base = (bid - 4096) * 16;
    const int wv_ = threadIdx.x >> 6;
    const int lane = threadIdx.x & 63;
#pragma unroll
    for (int it = 0; it < 4; ++it) {
      int gw = base + it * 4 + wv_;
      int mv = mask[(size_t)gw * 64 + lane];
      unsigned long long bm = __ballot(mv != 0);
      if (lane == 0) bits[gw] = bm;
    }
  }
}

// --- fused QKV GEMM, fp32 A inputs with reg prefetch ---------------------
// z=0: Qp = (q@Wq^T+bq)*0.125*log2e ; z=1: Kp ; z=2: Vt[b,h,d,s].
__global__ __launch_bounds__(256) void gemm_qkv(
    const float* __restrict__ qf, const float* __restrict__ kf,
    const float* __restrict__ vf, const __hip_bfloat16* __restrict__ wq,
    const __hip_bfloat16* __restrict__ wk,
    const __hip_bfloat16* __restrict__ wv, const float* __restrict__ bq,
    const float* __restrict__ bk_, const float* __restrict__ bv_,
    __hip_bfloat16* __restrict__ Qp, __hip_bfloat16* __restrict__ Kp,
    __hip_bfloat16* __restrict__ Vtp) {
  constexpr int N = 1024, K = 1024;
  const int fid = blockIdx.x + 8 * (blockIdx.y + 32 * blockIdx.z);
  const int nid = (fid & 7) * 96 + (fid >> 3);
  const int bx = nid & 7;
  const int by = (nid >> 3) & 31;
  const int z = nid >> 8;

  const float* Af = z == 0 ? qf : z == 1 ? kf : vf;
  const __hip_bfloat16* Bw = z == 0 ? wq : z == 1 ? wk : wv;
  const float* bias = z == 0 ? bq : z == 1 ? bk_ : bv_;

  __shared__ __hip_bfloat16 sA[128 * 32];
  __shared__ __hip_bfloat16 sB[128 * 32];
  const int tid = threadIdx.x;
  const int lane = tid & 63;
  const int wid = tid >> 6;
  const int wr = wid >> 1;
  const int wc = wid & 1;
  const int m0 = by * 128;
  const int n0 = bx * 128;
  const int srow = tid >> 2;
  const int scol = (tid & 3) * 8;

  f32x4 acc[4][4] = {};
  const int fr = lane & 15;
  const int fk = (lane >> 4) * 8;

  const float* a0base = Af + (size_t)(m0 + srow) * K + scol;
  const float* a1base = Af + (size_t)(m0 + 64 + srow) * K + scol;

  // prologue: A(k0=0) into regs
  float4 x0 = *(const float4*)(a0base);
  float4 x1 = *(const float4*)(a0base + 4);
  float4 y0 = *(const float4*)(a1base);
  float4 y1 = *(const float4*)(a1base + 4);

  for (int k0 = 0; k0 < K; k0 += 32) {
    // write A(k0) from regs (cvt_pk) into LDS; B via async gload
    u32x4 pa = {cvt_pk_bf16(x0.x, x0.y), cvt_pk_bf16(x0.z, x0.w),
                cvt_pk_bf16(x1.x, x1.y), cvt_pk_bf16(x1.z, x1.w)};
    u32x4 pb = {cvt_pk_bf16(y0.x, y0.y), cvt_pk_bf16(y0.z, y0.w),
                cvt_pk_bf16(y1.x, y1.y), cvt_pk_bf16(y1.z, y1.w)};
    *(u32x4*)(sA + tid * 8) = pa;
    *(u32x4*)(sA + 2048 + tid * 8) = pb;
    gload16(Bw + (size_t)(n0 + srow) * K + k0 + scol, sB + tid * 8);
    gload16(Bw + (size_t)(n0 + 64 + srow) * K + k0 + scol, sB + 2048 + tid * 8);
    __syncthreads();

    // issue A(k0+32) loads AFTER the barrier -> hidden under compute
    if (k0 + 32 < K) {
      x0 = *(const float4*)(a0base + k0 + 32);
      x1 = *(const float4*)(a0base + k0 + 36);
      y0 = *(const float4*)(a1base + k0 + 32);
      y1 = *(const float4*)(a1base + k0 + 36);
    }

    s16x8 af[4], bfr[4];
#pragma unroll
    for (int mi = 0; mi < 4; ++mi)
      af[mi] = *(const s16x8*)(sA + (wr * 64 + mi * 16 + fr) * 32 + fk);
#pragma unroll
    for (int ni = 0; ni < 4; ++ni)
      bfr[ni] = *(const s16x8*)(sB + (wc * 64 + ni * 16 + fr) * 32 + fk);
#pragma unroll
    for (int mi = 0; mi < 4; ++mi)
#pragma unroll
      for (int ni = 0; ni < 4; ++ni)
        acc[mi][ni] = mfma16x16x32(af[mi], bfr[ni], acc[mi][ni]);
    __syncthreads();
  }

  const int fq = (lane >> 4) * 4;
#pragma unroll
  for (int mi = 0; mi < 4; ++mi) {
#pragma unroll
    for (int ni = 0; ni < 4; ++ni) {
      const int row = m0 + wr * 64 + mi * 16 + fq;
      const int col = n0 + wc * 64 + ni * 16 + fr;
      const float bv = bias[col];
      f32x4 v = acc[mi][ni];
      if (z == 2) {
        ushort4 pk;
        pk.x = bf16bits(v[0] + bv);
        pk.y = bf16bits(v[1] + bv);
        pk.z = bf16bits(v[2] + bv);
        pk.w = bf16bits(v[3] + bv);
        const int bb = row >> 11;
        const int s = row & 2047;
        size_t vtrow = ((size_t)(bb * 16) + (col >> 6)) * 64 + (col & 63);
        *(ushort4*)(Vtp + vtrow * 2048 + s) = pk;
      } else if (z == 1) {
#pragma unroll
        for (int r = 0; r < 4; ++r)
          Kp[(size_t)(row + r) * N + col] = __float2bfloat16(v[r] + bv);
      } else {
#pragma unroll
        for (int r = 0; r < 4; ++r)
          Qp[(size_t)(row + r) * N + col] =
              __float2bfloat16((v[r] + bv) * 0.18033688f);  // 0.125*log2(e)
      }
    }
  }
}

// --- out GEMM: C = A @ Bw^T + bias (f32 out), 64x128 tile, 512 blocks ----
__global__ __launch_bounds__(256) void gemm_out(
    const __hip_bfloat16* __restrict__ A, const __hip_bfloat16* __restrict__ Bw,
    const float* __restrict__ bias, float* __restrict__ Cout) {
  constexpr int N = 1024, K = 1024;
  const int fid = blockIdx.x + 8 * blockIdx.y;
  const int nid = (fid & 7) * 64 + (fid >> 3);
  const int bx = nid & 7;
  const int by = nid >> 3;  // 0..63

  __shared__ __hip_bfloat16 sA[64 * 32];
  __shared__ __hip_bfloat16 sB[128 * 32];
  const int tid = threadIdx.x;
  const int lane = tid & 63;
  const int wid = tid >> 6;
  const int wr = wid >> 1;
  const int wc = wid & 1;
  const int m0 = by * 64;
  const int n0 = bx * 128;
  const int srow = tid >> 2;
  const int scol = (tid & 3) * 8;

  f32x4 acc[2][4] = {};
  const int fr = lane & 15;
  const int fk = (lane >> 4) * 8;

  for (int k0 = 0; k0 < K; k0 += 32) {
    gload16(A + (size_t)(m0 + srow) * K + k0 + scol, sA + tid * 8);
    gload16(Bw + (size_t)(n0 + srow) * K + k0 + scol, sB + tid * 8);
    gload16(Bw + (size_t)(n0 + 64 + srow) * K + k0 + scol, sB + 2048 + tid * 8);
    __syncthreads();
    s16x8 af[2], bfr[4];
#pragma unroll
    for (int mi = 0; mi < 2; ++mi)
      af[mi] = *(const s16x8*)(sA + (wr * 32 + mi * 16 + fr) * 32 + fk);
#pragma unroll
    for (int ni = 0; ni < 4; ++ni)
      bfr[ni] = *(const s16x8*)(sB + (wc * 64 + ni * 16 + fr) * 32 + fk);
#pragma unroll
    for (int mi = 0; mi < 2; ++mi)
#pragma unroll
      for (int ni = 0; ni < 4; ++ni)
        acc[mi][ni] = mfma16x16x32(af[mi], bfr[ni], acc[mi][ni]);
    __syncthreads();
  }

  const int fq = (lane >> 4) * 4;
#pragma unroll
  for (int mi = 0; mi < 2; ++mi) {
#pragma unroll
    for (int ni = 0; ni < 4; ++ni) {
      const int row = m0 + wr * 32 + mi * 16 + fq;
      const int col = n0 + wc * 64 + ni * 16 + fr;
      const float bv = bias[col];
      f32x4 v = acc[mi][ni];
#pragma unroll
      for (int r = 0; r < 4; ++r)
        Cout[(size_t)(row + r) * N + col] = v[r] + bv;
    }
  }
}

// --- flash attention: 32x32 MFMA, in-register P, KVBLK=128, ILP-paired ---
__global__ __launch_bounds__(256) void attn_kernel(
    const __hip_bfloat16* __restrict__ Q, const __hip_bfloat16* __restrict__ Kb,
    const __hip_bfloat16* __restrict__ Vt,
    const unsigned long long* __restrict__ gbits,
    __hip_bfloat16* __restrict__ O, int S) {
  __shared__ __hip_bfloat16 sK[2][2][64 * 64];   // [buf][kv-half][kv][d]
  __shared__ __hip_bfloat16 sVT[2][2][64 * 64];  // [buf][kv-half][d][kv]

  const int tid = threadIdx.x;
  const int lane = tid & 63;
  const int wid = tid >> 6;  // 0..3
  const int fid = blockIdx.x + 16 * blockIdx.y;
  const int nid = (fid & 7) * 64 + (fid >> 3);
  const int qblk = nid & 15;
  const int bh = nid >> 4;
  const int q0 = qblk * 128;
  const int b = bh >> 4;
  const size_t rowbase = (size_t)b * S * 1024 + (size_t)(bh & 15) * 64;
  const size_t vtbase = (size_t)bh * 64;

  const int l31 = lane & 31;
  const int h2 = lane >> 5;

  const int qw = q0 + wid * 32 + l31;
  s16x8 aq[4];
#pragma unroll
  for (int c2 = 0; c2 < 4; ++c2)
    aq[c2] =
        *(const s16x8*)(Q + rowbase + (size_t)qw * 1024 + c2 * 16 + h2 * 8);

  f32x16 o0 = {}, o1 = {}, lacc = {};
  s16x8 ones;
#pragma unroll
  for (int j = 0; j < 8; ++j) ones[j] = (short)0x3F80;  // bf16 1.0

  const unsigned long long* bitrow = gbits + ((size_t)b * S + qw) * (S / 64);

  const int lrow = lane >> 3;
  const int lg = ((lane & 7) ^ lrow) * 8;
  auto STAGE = [&](const int buf, int kv0) __attribute__((always_inline)) {
#pragma unroll
    for (int h = 0; h < 2; ++h) {
#pragma unroll
      for (int i = 0; i < 2; ++i) {
        const int rr = wid * 2 + i;
        const int rowi = rr * 8 + lrow;
        gload16(Kb + rowbase + (size_t)(kv0 + h * 64 + rowi) * 1024 + lg,
                &sK[buf][h][rr * 512 + lane * 8]);
        gload16(Vt + (vtbase + rowi) * 2048 + kv0 + h * 64 + lg,
                &sVT[buf][h][rr * 512 + lane * 8]);
      }
    }
  };

  // softmax+pack one 32-kv subtile (p = bits(exp2(s)) & sext(maskbit))
  auto packP = [&](const f32x16& sc, unsigned mm, s16x8& A0,
                   s16x8& A1) __attribute__((always_inline)) {
    float p[16];
#pragma unroll
    for (int reg = 0; reg < 16; ++reg) {
      float e = EXP2F(sc[reg]);
      const int bit = (reg & 3) + 8 * (reg >> 2);
      int m = ((int)(mm << (31 - bit))) >> 31;
      unsigned pe = __builtin_bit_cast(unsigned, e) & (unsigned)m;
      p[reg] = __builtin_bit_cast(float, pe);
    }
    unsigned w0t0 = cvt_pk_bf16(p[0], p[1]), w0t1 = cvt_pk_bf16(p[2], p[3]);
    unsigned w1t0 = cvt_pk_bf16(p[4], p[5]), w1t1 = cvt_pk_bf16(p[6], p[7]);
    unsigned w2t0 = cvt_pk_bf16(p[8], p[9]), w2t1 = cvt_pk_bf16(p[10], p[11]);
    unsigned w3t0 = cvt_pk_bf16(p[12], p[13]), w3t1 = cvt_pk_bf16(p[14], p[15]);
    asm("v_permlane32_swap_b32 %0, %1" : "+v"(w0t0), "+v"(w1t0));
    asm("v_permlane32_swap_b32 %0, %1" : "+v"(w0t1), "+v"(w1t1));
    asm("v_permlane32_swap_b32 %0, %1" : "+v"(w2t0), "+v"(w3t0));
    asm("v_permlane32_swap_b32 %0, %1" : "+v"(w2t1), "+v"(w3t1));
    u32x4 qa0 = {w0t0, w0t1, w1t0, w1t1};
    u32x4 qa1 = {w2t0, w2t1, w3t0, w3t1};
    A0 = __builtin_bit_cast(s16x8, qa0);
    A1 = __builtin_bit_cast(s16x8, qa1);
  };

  STAGE(0, 0);
  unsigned long long wc0 = bitrow[0], wc1 = bitrow[1];
  unsigned long long wn0 = 0, wn1 = 0;

  const int ntiles = S / 128;  // 16

  auto tile_body = [&](const int buf, int t) __attribute__((always_inline)) {
    __syncthreads();

    if (t + 1 < ntiles) {
      STAGE(buf ^ 1, (t + 1) * 128);
      wn0 = bitrow[2 * t + 2];
      wn1 = bitrow[2 * t + 3];
    }

#pragma unroll
    for (int kh = 0; kh < 2; ++kh) {
      const __hip_bfloat16* sKc = &sK[buf][kh][0];
      const __hip_bfloat16* sVc = &sVT[buf][kh][0];
      const unsigned long long wcv = kh ? wc1 : wc0;

      f32x16 s0 = {}, s1 = {};
#pragma unroll
      for (int c2 = 0; c2 < 4; ++c2) {
        s16x8 ak0 = *(const s16x8*)(sKc + KSWZ(l31, c2 * 16 + h2 * 8));
        s16x8 ak1 = *(const s16x8*)(sKc + KSWZ(32 + l31, c2 * 16 + h2 * 8));
        s0 = mfma32x32x16(ak0, aq[c2], s0);
        s1 = mfma32x32x16(ak1, aq[c2], s1);
      }

      s16x8 v000 = *(const s16x8*)(sVc + KSWZ(l31, h2 * 8));
      s16x8 v001 = *(const s16x8*)(sVc + KSWZ(l31, 16 + h2 * 8));
      s16x8 v010 = *(const s16x8*)(sVc + KSWZ(32 + l31, h2 * 8));
      s16x8 v011 = *(const s16x8*)(sVc + KSWZ(32 + l31, 16 + h2 * 8));
      s16x8 v100 = *(const s16x8*)(sVc + KSWZ(l31, 32 + h2 * 8));
      s16x8 v101 = *(const s16x8*)(sVc + KSWZ(l31, 32 + 16 + h2 * 8));
      s16x8 v110 = *(const s16x8*)(sVc + KSWZ(32 + l31, 32 + h2 * 8));
      s16x8 v111 = *(const s16x8*)(sVc + KSWZ(32 + l31, 32 + 16 + h2 * 8));

      s16x8 A00, A01, A10, A11;
      packP(s0, (unsigned)(wcv >> (h2 * 4)), A00, A01);
      o0 = mfma32x32x16(A00, v000, o0);
      o1 = mfma32x32x16(A00, v010, o1);
      lacc = mfma32x32x16(A00, ones, lacc);
      packP(s1, (unsigned)(wcv >> (32 + h2 * 4)), A10, A11);
      o0 = mfma32x32x16(A01, v001, o0);
      o1 = mfma32x32x16(A01, v011, o1);
      lacc = mfma32x32x16(A01, ones, lacc);
      o0 = mfma32x32x16(A10, v100, o0);
      o1 = mfma32x32x16(A10, v110, o1);
      lacc = mfma32x32x16(A10, ones, lacc);
      o0 = mfma32x32x16(A11, v101, o0);
      o1 = mfma32x32x16(A11, v111, o1);
      lacc = mfma32x32x16(A11, ones, lacc);
    }
    wc0 = wn0;
    wc1 = wn1;
  };

  for (int tb = 0; tb < ntiles / 2; ++tb) {
    tile_body(0, 2 * tb);
    tile_body(1, 2 * tb + 1);
  }

#pragma unroll
  for (int reg = 0; reg < 16; ++reg) {
    const float inv = RCPF(lacc[reg]);
    const int qr = (reg & 3) + 8 * (reg >> 2) + 4 * h2;
    const size_t base = rowbase + (size_t)(q0 + wid * 32 + qr) * 1024;
    O[base + 0 * 32 + l31] = __float2bfloat16(o0[reg] * inv);
    O[base + 1 * 32 + l31] = __float2bfloat16(o1[reg] * inv);
  }
}

extern "C" void kernel_launch(void* const* d_in, const int* in_sizes, int n_in,
                              void* d_out, int out_size, void* d_ws,
                              size_t ws_size, hipStream_t stream) {
  const float* query = (const float*)d_in[0];
  const float* key = (const float*)d_in[1];
  const float* value = (const float*)d_in[2];
  const int* mask = (const int*)d_in[3];
  const float* Wq = (const float*)d_in[4];
  const float* bq = (const float*)d_in[5];
  const float* Wk = (const float*)d_in[6];
  const float* bk = (const float*)d_in[7];
  const float* Wv = (const float*)d_in[8];
  const float* bv = (const float*)d_in[9];
  const float* Wo = (const float*)d_in[10];
  const float* bo = (const float*)d_in[11];

  const int B = 2, S = 2048, D = 1024;
  const int M = B * S;
  const size_t MB = 1024u * 1024u;

  char* ws = (char*)d_ws;
  __hip_bfloat16* wqb = (__hip_bfloat16*)(ws + 24 * MB);
  __hip_bfloat16* wkb = (__hip_bfloat16*)(ws + 26 * MB);
  __hip_bfloat16* wvb = (__hip_bfloat16*)(ws + 28 * MB);
  __hip_bfloat16* wob = (__hip_bfloat16*)(ws + 30 * MB);
  __hip_bfloat16* Qp = (__hip_bfloat16*)(ws + 32 * MB);
  __hip_bfloat16* Kp = (__hip_bfloat16*)(ws + 40 * MB);
  __hip_bfloat16* Vtp = (__hip_bfloat16*)(ws + 48 * MB);
  __hip_bfloat16* Ob = (__hip_bfloat16*)(ws + 56 * MB);
  unsigned long long* bits = (unsigned long long*)(ws + 64 * MB);

  prep_kernel<<<dim3(12288), dim3(256), 0, stream>>>(
      Wq, Wk, Wv, Wo, mask, wqb, wkb, wvb, wob, bits);

  gemm_qkv<<<dim3(D / 128, M / 128, 3), dim3(256), 0, stream>>>(
      query, key, value, wqb, wkb, wvb, bq, bk, bv, Qp, Kp, Vtp);

  attn_kernel<<<dim3(S / 128, B * 16), dim3(256), 0, stream>>>(Qp, Kp, Vtp,
                                                               bits, Ob, S);

  gemm_out<<<dim3(D / 128, M / 64), dim3(256), 0, stream>>>(Ob, wob, bo,
                                                            (float*)d_out);
}